// Round 1
// baseline (1793.362 us; speedup 1.0000x reference)
//
#include <hip/hip_runtime.h>

// Problem constants (fixed by the reference)
#define N_NODES   50000
#define N_EDGES   800000
#define IN_DIM    128
#define HID       64
#define OUT_DIM   128
#define N_GRAPHS  128

// Workspace layout (float offsets)
#define OFF_H     0
#define OFF_TMP   (N_NODES * HID)            // 3,200,000
#define OFF_AGGR  (2 * N_NODES * HID)        // 6,400,000
#define OFF_SUMS  (3 * N_NODES * HID)        // 9,600,000
#define OFF_CNT   (OFF_SUMS + N_GRAPHS * OUT_DIM)
#define WS_FLOATS (OFF_CNT + N_GRAPHS)

// ---------------------------------------------------------------- zero fill
__global__ void k_zero(float* __restrict__ p, int n) {
    int i = blockIdx.x * blockDim.x + threadIdx.x;
    int stride = gridDim.x * blockDim.x;
    for (; i < n; i += stride) p[i] = 0.0f;
}

// ---------------------------------------------------------------- proj_in
// h[n][c] = b[c] + sum_k x[n][k] * W[k][c]     (x: [N,128], W: [128,64])
// wave-per-node: lane = output col; x row held in 2 regs, broadcast via shfl.
__global__ __launch_bounds__(256) void k_proj_in(
        const float* __restrict__ x, const float* __restrict__ W,
        const float* __restrict__ b, float* __restrict__ h) {
    __shared__ float Wl[IN_DIM * HID];  // 32 KiB
    for (int i = threadIdx.x; i < IN_DIM * HID; i += 256) Wl[i] = W[i];
    __syncthreads();
    const int wv = threadIdx.x >> 6;
    const int lane = threadIdx.x & 63;
    const float bl = b[lane];
    for (int node = blockIdx.x * 4 + wv; node < N_NODES; node += gridDim.x * 4) {
        const float xa = x[node * IN_DIM + lane];
        const float xb = x[node * IN_DIM + 64 + lane];
        float acc = bl;
#pragma unroll
        for (int k = 0; k < 64; ++k)
            acc += __shfl(xa, k, 64) * Wl[k * HID + lane];
#pragma unroll
        for (int k = 0; k < 64; ++k)
            acc += __shfl(xb, k, 64) * Wl[(k + 64) * HID + lane];
        h[node * HID + lane] = acc;
    }
}

// ---------------------------------------------------------------- edge scatter
// aggr[dst] += h[src], one thread per (edge, float4-chunk)
__global__ __launch_bounds__(256) void k_scatter(
        const int* __restrict__ ei, const float* __restrict__ h,
        float* __restrict__ aggr) {
    const int tid = blockIdx.x * blockDim.x + threadIdx.x;
    const int e = tid >> 4;          // 16 chunks of float4 per edge
    if (e >= N_EDGES) return;
    const int c = (tid & 15) * 4;
    const int src = ei[e];
    const int dst = ei[N_EDGES + e];
    const float4 v = *(const float4*)(h + src * HID + c);
    float* a = aggr + dst * HID + c;
    atomicAdd(a + 0, v.x);
    atomicAdd(a + 1, v.y);
    atomicAdd(a + 2, v.z);
    atomicAdd(a + 3, v.w);
}

// ---------------------------------------------------------------- GIN MLP
// hout = relu( relu((h+aggr) @ W1 + b1) @ W2 + b2 )
// wave-per-node; W1/W2 in LDS; activation vector broadcast via shfl.
__global__ __launch_bounds__(256) void k_gin_mlp(
        const float* __restrict__ h, const float* __restrict__ aggr,
        const float* __restrict__ W1, const float* __restrict__ b1,
        const float* __restrict__ W2, const float* __restrict__ b2,
        float* __restrict__ hout) {
    __shared__ float W1l[HID * HID];  // 16 KiB
    __shared__ float W2l[HID * HID];  // 16 KiB
    for (int i = threadIdx.x; i < HID * HID; i += 256) {
        W1l[i] = W1[i];
        W2l[i] = W2[i];
    }
    __syncthreads();
    const int wv = threadIdx.x >> 6;
    const int lane = threadIdx.x & 63;
    const float b1l = b1[lane];
    const float b2l = b2[lane];
    for (int node = blockIdx.x * 4 + wv; node < N_NODES; node += gridDim.x * 4) {
        const float v = h[node * HID + lane] + aggr[node * HID + lane];
        float u = b1l;
#pragma unroll
        for (int k = 0; k < HID; ++k)
            u += __shfl(v, k, 64) * W1l[k * HID + lane];
        u = fmaxf(u, 0.0f);
        float o = b2l;
#pragma unroll
        for (int k = 0; k < HID; ++k)
            o += __shfl(u, k, 64) * W2l[k * HID + lane];
        hout[node * HID + lane] = fmaxf(o, 0.0f);
    }
}

// ---------------------------------------------------------------- proj_out + mean-pool partial
// o[n][c] = bo[c] + sum_k h[n][k] * Wo[k][c]; accumulate per-graph sums
// exploiting that `batch` is sorted: register-accumulate, flush on change.
#define POOL_CHUNK 64
__global__ __launch_bounds__(128) void k_out_pool(
        const float* __restrict__ h, const int* __restrict__ batch,
        const float* __restrict__ Wo, const float* __restrict__ bo,
        float* __restrict__ sums, float* __restrict__ counts) {
    __shared__ float Wl[HID * OUT_DIM];  // 32 KiB
    for (int i = threadIdx.x; i < HID * OUT_DIM; i += 128) Wl[i] = Wo[i];
    __syncthreads();
    const int c = threadIdx.x;       // 0..127 output col
    const int lane = threadIdx.x & 63;
    const float bl = bo[c];
    const int n0 = blockIdx.x * POOL_CHUNK;
    if (n0 >= N_NODES) return;
    const int n1 = min(n0 + POOL_CHUNK, N_NODES);
    int cur = batch[n0];
    float acc = 0.0f;
    float cnt = 0.0f;
    for (int n = n0; n < n1; ++n) {
        const int g = batch[n];                    // uniform per iteration
        const float r = h[n * HID + lane];         // each wave holds the row
        float o = bl;
#pragma unroll
        for (int k = 0; k < HID; ++k)
            o += __shfl(r, k, 64) * Wl[k * OUT_DIM + c];
        if (g != cur) {
            atomicAdd(&sums[cur * OUT_DIM + c], acc);
            if (c == 0) atomicAdd(&counts[cur], cnt);
            acc = 0.0f; cnt = 0.0f; cur = g;
        }
        acc += o;
        cnt += 1.0f;
    }
    atomicAdd(&sums[cur * OUT_DIM + c], acc);
    if (c == 0) atomicAdd(&counts[cur], cnt);
}

// ---------------------------------------------------------------- finalize
__global__ void k_final(const float* __restrict__ sums,
                        const float* __restrict__ counts,
                        float* __restrict__ out) {
    const int i = blockIdx.x * blockDim.x + threadIdx.x;
    if (i < N_GRAPHS * OUT_DIM) {
        const float cnt = counts[i >> 7];  // i / OUT_DIM
        out[i] = sums[i] / fmaxf(cnt, 1.0f);
    }
}

// ---------------------------------------------------------------- launch
extern "C" void kernel_launch(void* const* d_in, const int* in_sizes, int n_in,
                              void* d_out, int out_size, void* d_ws, size_t ws_size,
                              hipStream_t stream) {
    const float* x     = (const float*)d_in[0];
    const int*   ei    = (const int*)d_in[1];
    const int*   batch = (const int*)d_in[2];
    const float* W_in  = (const float*)d_in[3];
    const float* b_in  = (const float*)d_in[4];
    const float* W1_0  = (const float*)d_in[5];
    const float* b1_0  = (const float*)d_in[6];
    const float* W2_0  = (const float*)d_in[7];
    const float* b2_0  = (const float*)d_in[8];
    const float* W1_1  = (const float*)d_in[9];
    const float* b1_1  = (const float*)d_in[10];
    const float* W2_1  = (const float*)d_in[11];
    const float* W2_1b = (const float*)d_in[12];  // b2_1
    const float* W_out = (const float*)d_in[13];
    const float* b_out = (const float*)d_in[14];
    float* out = (float*)d_out;

    float* ws   = (float*)d_ws;
    float* h    = ws + OFF_H;
    float* tmp  = ws + OFF_TMP;
    float* aggr = ws + OFF_AGGR;
    float* sums = ws + OFF_SUMS;
    float* cnts = ws + OFF_CNT;

    const int scatter_blocks = (N_EDGES * 16 + 255) / 256;  // 50000
    const int pool_blocks = (N_NODES + POOL_CHUNK - 1) / POOL_CHUNK;

    // zero aggr + sums + counts (contiguous region)
    k_zero<<<1024, 256, 0, stream>>>(aggr, N_NODES * HID + N_GRAPHS * OUT_DIM + N_GRAPHS);
    // proj_in
    k_proj_in<<<2048, 256, 0, stream>>>(x, W_in, b_in, h);
    // conv 0
    k_scatter<<<scatter_blocks, 256, 0, stream>>>(ei, h, aggr);
    k_gin_mlp<<<2048, 256, 0, stream>>>(h, aggr, W1_0, b1_0, W2_0, b2_0, tmp);
    // conv 1
    k_zero<<<1024, 256, 0, stream>>>(aggr, N_NODES * HID);
    k_scatter<<<scatter_blocks, 256, 0, stream>>>(ei, tmp, aggr);
    k_gin_mlp<<<2048, 256, 0, stream>>>(tmp, aggr, W1_1, b1_1, W2_1, W2_1b, h);
    // proj_out + pool
    k_out_pool<<<pool_blocks, 128, 0, stream>>>(h, batch, W_out, b_out, sums, cnts);
    k_final<<<(N_GRAPHS * OUT_DIM + 255) / 256, 256, 0, stream>>>(sums, cnts, out);
}

// Round 2
// 891.799 us; speedup vs baseline: 2.0109x; 2.0109x over previous
//
#include <hip/hip_runtime.h>

// Problem constants (fixed by the reference)
#define N_NODES   50000
#define N_EDGES   800000
#define IN_DIM    128
#define HID       64
#define OUT_DIM   128
#define N_GRAPHS  128

// Workspace layout in 4-byte words.
// [deg|sums|cnts] are contiguous so one zero-fill covers all three.
#define OFF_DEG     0                          // int[50000]
#define OFF_SUMS    50000                      // float[16384]
#define OFF_CNT     66384                      // float[128]
#define ZERO_WORDS  66512
#define OFF_ROWPTR  66512                      // int[50001]
#define OFF_CURSOR  116516                     // int[50000]
#define OFF_SRCL    166516                     // int[800000]
#define OFF_H       966516                     // float[3,200,000]
#define OFF_TMP     4166516                    // float[3,200,000]

// ---------------------------------------------------------------- zero fill (works for int/float: 0 bits)
__global__ void k_zero(unsigned int* __restrict__ p, int n) {
    int i = blockIdx.x * blockDim.x + threadIdx.x;
    int stride = gridDim.x * blockDim.x;
    for (; i < n; i += stride) p[i] = 0u;
}

// ---------------------------------------------------------------- CSR build: histogram of dst
__global__ __launch_bounds__(256) void k_hist(const int* __restrict__ ei,
                                              int* __restrict__ deg) {
    const int e = blockIdx.x * blockDim.x + threadIdx.x;
    if (e < N_EDGES) atomicAdd(&deg[ei[N_EDGES + e]], 1);
}

// ---------------------------------------------------------------- CSR build: exclusive scan (single block)
__global__ __launch_bounds__(1024) void k_scan(const int* __restrict__ deg,
                                               int* __restrict__ rowptr,
                                               int* __restrict__ cursor) {
    __shared__ int part[1024];
    const int t = threadIdx.x;
    const int chunk = (N_NODES + 1023) / 1024;  // 49
    const int beg = t * chunk;
    const int end = min(beg + chunk, N_NODES);
    int s = 0;
    for (int i = beg; i < end; ++i) s += deg[i];
    part[t] = s;
    __syncthreads();
    if (t == 0) {
        int run = 0;
        for (int i = 0; i < 1024; ++i) { int v = part[i]; part[i] = run; run += v; }
    }
    __syncthreads();
    int run = part[t];
    for (int i = beg; i < end; ++i) {
        rowptr[i] = run;
        cursor[i] = run;
        run += deg[i];
    }
    if (t == 1023) rowptr[N_NODES] = run;  // == N_EDGES
}

// ---------------------------------------------------------------- CSR build: bucket fill
__global__ __launch_bounds__(256) void k_fill(const int* __restrict__ ei,
                                              int* __restrict__ cursor,
                                              int* __restrict__ srclist) {
    const int e = blockIdx.x * blockDim.x + threadIdx.x;
    if (e >= N_EDGES) return;
    const int dst = ei[N_EDGES + e];
    const int pos = atomicAdd(&cursor[dst], 1);
    srclist[pos] = ei[e];
}

// ---------------------------------------------------------------- proj_in
// h[n][c] = b[c] + sum_k x[n][k] * W[k][c]     (x: [N,128], W: [128,64])
__global__ __launch_bounds__(256) void k_proj_in(
        const float* __restrict__ x, const float* __restrict__ W,
        const float* __restrict__ b, float* __restrict__ h) {
    __shared__ float Wl[IN_DIM * HID];  // 32 KiB
    for (int i = threadIdx.x; i < IN_DIM * HID; i += 256) Wl[i] = W[i];
    __syncthreads();
    const int wv = threadIdx.x >> 6;
    const int lane = threadIdx.x & 63;
    const float bl = b[lane];
    for (int node = blockIdx.x * 4 + wv; node < N_NODES; node += gridDim.x * 4) {
        const float xa = x[node * IN_DIM + lane];
        const float xb = x[node * IN_DIM + 64 + lane];
        float acc = bl;
#pragma unroll
        for (int k = 0; k < 64; ++k)
            acc += __shfl(xa, k, 64) * Wl[k * HID + lane];
#pragma unroll
        for (int k = 0; k < 64; ++k)
            acc += __shfl(xb, k, 64) * Wl[(k + 64) * HID + lane];
        h[node * HID + lane] = acc;
    }
}

// ---------------------------------------------------------------- fused GIN conv
// v = h[node] + sum_{src in in-edges(node)} h[src]   (CSR gather, no atomics)
// hout = relu( relu(v @ W1 + b1) @ W2 + b2 )
__global__ __launch_bounds__(256) void k_gin_fused(
        const float* __restrict__ h,
        const int* __restrict__ rowptr, const int* __restrict__ srclist,
        const float* __restrict__ W1, const float* __restrict__ b1,
        const float* __restrict__ W2, const float* __restrict__ b2,
        float* __restrict__ hout) {
    __shared__ float W1l[HID * HID];  // 16 KiB
    __shared__ float W2l[HID * HID];  // 16 KiB
    for (int i = threadIdx.x; i < HID * HID; i += 256) {
        W1l[i] = W1[i];
        W2l[i] = W2[i];
    }
    __syncthreads();
    const int wv = threadIdx.x >> 6;
    const int lane = threadIdx.x & 63;
    const float b1l = b1[lane];
    const float b2l = b2[lane];
    for (int node = blockIdx.x * 4 + wv; node < N_NODES; node += gridDim.x * 4) {
        const int beg = rowptr[node];
        const int end = rowptr[node + 1];
        float v = h[node * HID + lane];
        // gather in chunks of 64: coalesced srclist read, shfl-broadcast indices
        for (int base = beg; base < end; base += 64) {
            const int rem = end - base;
            const int cnt = rem < 64 ? rem : 64;
            const int s = (lane < rem) ? srclist[base + lane] : 0;
            for (int k = 0; k < cnt; ++k) {
                const int sk = __shfl(s, k, 64);
                v += h[sk * HID + lane];
            }
        }
        float u = b1l;
#pragma unroll
        for (int k = 0; k < HID; ++k)
            u += __shfl(v, k, 64) * W1l[k * HID + lane];
        u = fmaxf(u, 0.0f);
        float o = b2l;
#pragma unroll
        for (int k = 0; k < HID; ++k)
            o += __shfl(u, k, 64) * W2l[k * HID + lane];
        hout[node * HID + lane] = fmaxf(o, 0.0f);
    }
}

// ---------------------------------------------------------------- proj_out + mean-pool partial
#define POOL_CHUNK 64
__global__ __launch_bounds__(128) void k_out_pool(
        const float* __restrict__ h, const int* __restrict__ batch,
        const float* __restrict__ Wo, const float* __restrict__ bo,
        float* __restrict__ sums, float* __restrict__ counts) {
    __shared__ float Wl[HID * OUT_DIM];  // 32 KiB
    for (int i = threadIdx.x; i < HID * OUT_DIM; i += 128) Wl[i] = Wo[i];
    __syncthreads();
    const int c = threadIdx.x;       // 0..127 output col
    const int lane = threadIdx.x & 63;
    const float bl = bo[c];
    const int n0 = blockIdx.x * POOL_CHUNK;
    if (n0 >= N_NODES) return;
    const int n1 = min(n0 + POOL_CHUNK, N_NODES);
    int cur = batch[n0];
    float acc = 0.0f;
    float cnt = 0.0f;
    for (int n = n0; n < n1; ++n) {
        const int g = batch[n];                    // uniform per iteration
        const float r = h[n * HID + lane];         // each wave holds the row
        float o = bl;
#pragma unroll
        for (int k = 0; k < HID; ++k)
            o += __shfl(r, k, 64) * Wl[k * OUT_DIM + c];
        if (g != cur) {
            atomicAdd(&sums[cur * OUT_DIM + c], acc);
            if (c == 0) atomicAdd(&counts[cur], cnt);
            acc = 0.0f; cnt = 0.0f; cur = g;
        }
        acc += o;
        cnt += 1.0f;
    }
    atomicAdd(&sums[cur * OUT_DIM + c], acc);
    if (c == 0) atomicAdd(&counts[cur], cnt);
}

// ---------------------------------------------------------------- finalize
__global__ void k_final(const float* __restrict__ sums,
                        const float* __restrict__ counts,
                        float* __restrict__ out) {
    const int i = blockIdx.x * blockDim.x + threadIdx.x;
    if (i < N_GRAPHS * OUT_DIM) {
        const float cnt = counts[i >> 7];  // i / OUT_DIM
        out[i] = sums[i] / fmaxf(cnt, 1.0f);
    }
}

// ---------------------------------------------------------------- launch
extern "C" void kernel_launch(void* const* d_in, const int* in_sizes, int n_in,
                              void* d_out, int out_size, void* d_ws, size_t ws_size,
                              hipStream_t stream) {
    const float* x     = (const float*)d_in[0];
    const int*   ei    = (const int*)d_in[1];
    const int*   batch = (const int*)d_in[2];
    const float* W_in  = (const float*)d_in[3];
    const float* b_in  = (const float*)d_in[4];
    const float* W1_0  = (const float*)d_in[5];
    const float* b1_0  = (const float*)d_in[6];
    const float* W2_0  = (const float*)d_in[7];
    const float* b2_0  = (const float*)d_in[8];
    const float* W1_1  = (const float*)d_in[9];
    const float* b1_1  = (const float*)d_in[10];
    const float* W2_1  = (const float*)d_in[11];
    const float* b2_1  = (const float*)d_in[12];
    const float* W_out = (const float*)d_in[13];
    const float* b_out = (const float*)d_in[14];
    float* out = (float*)d_out;

    unsigned int* wsw = (unsigned int*)d_ws;
    int*   deg    = (int*)(wsw + OFF_DEG);
    float* sums   = (float*)(wsw + OFF_SUMS);
    float* cnts   = (float*)(wsw + OFF_CNT);
    int*   rowptr = (int*)(wsw + OFF_ROWPTR);
    int*   cursor = (int*)(wsw + OFF_CURSOR);
    int*   srcl   = (int*)(wsw + OFF_SRCL);
    float* h      = (float*)(wsw + OFF_H);
    float* tmp    = (float*)(wsw + OFF_TMP);

    const int eblocks = (N_EDGES + 255) / 256;  // 3125
    const int pool_blocks = (N_NODES + POOL_CHUNK - 1) / POOL_CHUNK;

    // zero deg + sums + counts (contiguous)
    k_zero<<<512, 256, 0, stream>>>(wsw, ZERO_WORDS);
    // CSR build (used by both convs)
    k_hist<<<eblocks, 256, 0, stream>>>(ei, deg);
    k_scan<<<1, 1024, 0, stream>>>(deg, rowptr, cursor);
    k_fill<<<eblocks, 256, 0, stream>>>(ei, cursor, srcl);
    // proj_in
    k_proj_in<<<2048, 256, 0, stream>>>(x, W_in, b_in, h);
    // conv 0 (gather + MLP fused)
    k_gin_fused<<<1280, 256, 0, stream>>>(h, rowptr, srcl, W1_0, b1_0, W2_0, b2_0, tmp);
    // conv 1
    k_gin_fused<<<1280, 256, 0, stream>>>(tmp, rowptr, srcl, W1_1, b1_1, W2_1, b2_1, h);
    // proj_out + pool
    k_out_pool<<<pool_blocks, 128, 0, stream>>>(h, batch, W_out, b_out, sums, cnts);
    k_final<<<(N_GRAPHS * OUT_DIM + 255) / 256, 256, 0, stream>>>(sums, cnts, out);
}

// Round 3
// 464.403 us; speedup vs baseline: 3.8617x; 1.9203x over previous
//
#include <hip/hip_runtime.h>

// Problem constants (fixed by the reference)
#define N_NODES   50000
#define N_EDGES   800000
#define IN_DIM    128
#define HID       64
#define OUT_DIM   128
#define N_GRAPHS  128

// Workspace layout in 4-byte words.
// [deg|sums|cnts] contiguous -> one zero-fill covers all three.
#define OFF_DEG     0                           // int[50000]
#define OFF_SUMS    50000                       // float[128*64] pooled-h sums
#define OFF_CNT     58192                       // float[128]
#define ZERO_WORDS  58320
#define OFF_ROWPTR  58320                       // int[50001]
#define OFF_CURSOR  108321                      // int[50000]
#define OFF_SRCL    158336                      // int[800000]   (16-aligned)
#define OFF_BUFA    958336                      // float[3,200,000]
#define OFF_BUFB    4158336                     // float[3,200,000]
// end = 7,358,336 words = 29.4 MB

// ---------------------------------------------------------------- zero fill
__global__ void k_zero(unsigned int* __restrict__ p, int n) {
    int i = blockIdx.x * blockDim.x + threadIdx.x;
    int stride = gridDim.x * blockDim.x;
    for (; i < n; i += stride) p[i] = 0u;
}

// ---------------------------------------------------------------- CSR build
__global__ __launch_bounds__(256) void k_hist(const int* __restrict__ ei,
                                              int* __restrict__ deg) {
    const int e = blockIdx.x * blockDim.x + threadIdx.x;
    if (e < N_EDGES) atomicAdd(&deg[ei[N_EDGES + e]], 1);
}

__global__ __launch_bounds__(1024) void k_scan(const int* __restrict__ deg,
                                               int* __restrict__ rowptr,
                                               int* __restrict__ cursor) {
    __shared__ int part[1024];
    const int t = threadIdx.x;
    const int chunk = (N_NODES + 1023) / 1024;  // 49
    const int beg = t * chunk;
    const int end = min(beg + chunk, N_NODES);
    int s = 0;
    for (int i = beg; i < end; ++i) s += deg[i];
    part[t] = s;
    __syncthreads();
    if (t == 0) {
        int run = 0;
        for (int i = 0; i < 1024; ++i) { int v = part[i]; part[i] = run; run += v; }
    }
    __syncthreads();
    int run = part[t];
    for (int i = beg; i < end; ++i) {
        rowptr[i] = run;
        cursor[i] = run;
        run += deg[i];
    }
    if (t == 1023) rowptr[N_NODES] = run;  // == N_EDGES
}

__global__ __launch_bounds__(256) void k_fill(const int* __restrict__ ei,
                                              int* __restrict__ cursor,
                                              int* __restrict__ srclist) {
    const int e = blockIdx.x * blockDim.x + threadIdx.x;
    if (e >= N_EDGES) return;
    const int dst = ei[N_EDGES + e];
    const int pos = atomicAdd(&cursor[dst], 1);
    srclist[pos] = ei[e];
}

// ---------------------------------------------------------------- aggregation (gather)
// v[n] = h[n] + sum_{src in in(n)} h[src]
// Wave = 4 nodes; 16-lane group per node; lane q = float4 chunk of the row.
// Edge loop unrolled x4 -> up to 16 independent 16B loads in flight per wave.
__global__ __launch_bounds__(256) void k_aggr(
        const float* __restrict__ h,
        const int* __restrict__ rowptr, const int* __restrict__ srclist,
        float* __restrict__ v) {
    const int t = threadIdx.x;
    const int wv = t >> 6;            // wave in block (0..3)
    const int lane = t & 63;
    const int g = lane >> 4;          // node group (0..3)
    const int q = lane & 15;          // float4 chunk (0..15)
    const int node = blockIdx.x * 16 + wv * 4 + g;   // N_NODES = 3125*16 exact

    const int beg = rowptr[node];
    const int end = rowptr[node + 1];

    float4 acc = *(const float4*)(h + (size_t)node * HID + q * 4);
    int e = beg;
    for (; e + 4 <= end; e += 4) {
        const int s0 = srclist[e];
        const int s1 = srclist[e + 1];
        const int s2 = srclist[e + 2];
        const int s3 = srclist[e + 3];
        const float4 a0 = *(const float4*)(h + (size_t)s0 * HID + q * 4);
        const float4 a1 = *(const float4*)(h + (size_t)s1 * HID + q * 4);
        const float4 a2 = *(const float4*)(h + (size_t)s2 * HID + q * 4);
        const float4 a3 = *(const float4*)(h + (size_t)s3 * HID + q * 4);
        acc.x += a0.x + a1.x + a2.x + a3.x;
        acc.y += a0.y + a1.y + a2.y + a3.y;
        acc.z += a0.z + a1.z + a2.z + a3.z;
        acc.w += a0.w + a1.w + a2.w + a3.w;
    }
    for (; e < end; ++e) {
        const int s = srclist[e];
        const float4 a = *(const float4*)(h + (size_t)s * HID + q * 4);
        acc.x += a.x; acc.y += a.y; acc.z += a.z; acc.w += a.w;
    }
    *(float4*)(v + (size_t)node * HID + q * 4) = acc;
}

// ---------------------------------------------------------------- GIN MLP (GEMM-tiled)
// hout = relu( relu(v @ W1 + b1) @ W2 + b2 ), 128 nodes per block,
// thread = 4 nodes x 8 cols. Activations in LDS stride 65 (==1 mod 32:
// conflict-free column reads; odd stride -> scalar staging writes).
#define S_A 65
__global__ __launch_bounds__(256) void k_mlp(
        const float* __restrict__ v,
        const float* __restrict__ W1, const float* __restrict__ b1,
        const float* __restrict__ W2, const float* __restrict__ b2,
        float* __restrict__ hout) {
    __shared__ float A[128 * S_A];          // 33.3 KB (reused for u)
    __shared__ float Wl[2 * HID * HID];     // 32 KB
    const int t = threadIdx.x;
    for (int i = t; i < HID * HID; i += 256) {
        Wl[i] = W1[i];
        Wl[HID * HID + i] = W2[i];
    }
    const int nb = blockIdx.x * 128;
    // stage v tile -> A[n][k]
    for (int i = t; i < 128 * (HID / 4); i += 256) {
        const int n = i >> 4;
        const int k4 = (i & 15) * 4;
        float4 val = make_float4(0.f, 0.f, 0.f, 0.f);
        if (nb + n < N_NODES)
            val = *(const float4*)(v + (size_t)(nb + n) * HID + k4);
        float* dst = &A[n * S_A + k4];
        dst[0] = val.x; dst[1] = val.y; dst[2] = val.z; dst[3] = val.w;
    }
    __syncthreads();

    const int ln = t & 31;                // node lane: nodes ln+32j
    const int c0 = (t >> 5) * 8;          // col octet
    float bb1[8], bb2[8];
#pragma unroll
    for (int c = 0; c < 8; ++c) { bb1[c] = b1[c0 + c]; bb2[c] = b2[c0 + c]; }

    float acc[4][8];
    // ---- layer 1
#pragma unroll
    for (int j = 0; j < 4; ++j)
#pragma unroll
        for (int c = 0; c < 8; ++c) acc[j][c] = bb1[c];
    for (int k = 0; k < HID; ++k) {
        float a[4];
#pragma unroll
        for (int j = 0; j < 4; ++j) a[j] = A[(ln + 32 * j) * S_A + k];
        const float4 wA = *(const float4*)&Wl[k * HID + c0];
        const float4 wB = *(const float4*)&Wl[k * HID + c0 + 4];
        const float w[8] = {wA.x, wA.y, wA.z, wA.w, wB.x, wB.y, wB.z, wB.w};
#pragma unroll
        for (int j = 0; j < 4; ++j)
#pragma unroll
            for (int c = 0; c < 8; ++c)
                acc[j][c] = fmaf(a[j], w[c], acc[j][c]);
    }
    __syncthreads();  // all layer-1 reads of A done
    // write u = relu(acc) into A[n][c]
#pragma unroll
    for (int j = 0; j < 4; ++j) {
        float* dst = &A[(ln + 32 * j) * S_A + c0];
#pragma unroll
        for (int c = 0; c < 8; ++c) dst[c] = fmaxf(acc[j][c], 0.0f);
    }
    __syncthreads();

    // ---- layer 2
#pragma unroll
    for (int j = 0; j < 4; ++j)
#pragma unroll
        for (int c = 0; c < 8; ++c) acc[j][c] = bb2[c];
    for (int k = 0; k < HID; ++k) {
        float a[4];
#pragma unroll
        for (int j = 0; j < 4; ++j) a[j] = A[(ln + 32 * j) * S_A + k];
        const float4 wA = *(const float4*)&Wl[HID * HID + k * HID + c0];
        const float4 wB = *(const float4*)&Wl[HID * HID + k * HID + c0 + 4];
        const float w[8] = {wA.x, wA.y, wA.z, wA.w, wB.x, wB.y, wB.z, wB.w};
#pragma unroll
        for (int j = 0; j < 4; ++j)
#pragma unroll
            for (int c = 0; c < 8; ++c)
                acc[j][c] = fmaf(a[j], w[c], acc[j][c]);
    }
    // relu + store
#pragma unroll
    for (int j = 0; j < 4; ++j) {
        const int n = nb + ln + 32 * j;
        if (n < N_NODES) {
            float4 o0, o1;
            o0.x = fmaxf(acc[j][0], 0.f); o0.y = fmaxf(acc[j][1], 0.f);
            o0.z = fmaxf(acc[j][2], 0.f); o0.w = fmaxf(acc[j][3], 0.f);
            o1.x = fmaxf(acc[j][4], 0.f); o1.y = fmaxf(acc[j][5], 0.f);
            o1.z = fmaxf(acc[j][6], 0.f); o1.w = fmaxf(acc[j][7], 0.f);
            *(float4*)(hout + (size_t)n * HID + c0) = o0;
            *(float4*)(hout + (size_t)n * HID + c0 + 4) = o1;
        }
    }
}

// ---------------------------------------------------------------- proj_in (GEMM-tiled, K=128)
// h[n][c] = b[c] + sum_k x[n][k] W[k][c]; 64 nodes/block, thread = 2 nodes x 8 cols.
#define S_X 129
__global__ __launch_bounds__(256) void k_proj_in(
        const float* __restrict__ x, const float* __restrict__ W,
        const float* __restrict__ b, float* __restrict__ h) {
    __shared__ float A[64 * S_X];           // 33 KB
    __shared__ float Wl[IN_DIM * HID];      // 32 KB
    const int t = threadIdx.x;
    for (int i = t; i < IN_DIM * HID; i += 256) Wl[i] = W[i];
    const int nb = blockIdx.x * 64;
    for (int i = t; i < 64 * (IN_DIM / 4); i += 256) {   // 2048 chunks
        const int n = i >> 5;
        const int k4 = (i & 31) * 4;
        float4 val = make_float4(0.f, 0.f, 0.f, 0.f);
        if (nb + n < N_NODES)
            val = *(const float4*)(x + (size_t)(nb + n) * IN_DIM + k4);
        float* dst = &A[n * S_X + k4];
        dst[0] = val.x; dst[1] = val.y; dst[2] = val.z; dst[3] = val.w;
    }
    __syncthreads();

    const int ln = t & 31;                // nodes ln, ln+32
    const int c0 = (t >> 5) * 8;
    float acc[2][8];
#pragma unroll
    for (int j = 0; j < 2; ++j)
#pragma unroll
        for (int c = 0; c < 8; ++c) acc[j][c] = b[c0 + c];
    for (int k = 0; k < IN_DIM; ++k) {
        const float a0 = A[ln * S_X + k];
        const float a1 = A[(ln + 32) * S_X + k];
        const float4 wA = *(const float4*)&Wl[k * HID + c0];
        const float4 wB = *(const float4*)&Wl[k * HID + c0 + 4];
        const float w[8] = {wA.x, wA.y, wA.z, wA.w, wB.x, wB.y, wB.z, wB.w};
#pragma unroll
        for (int c = 0; c < 8; ++c) {
            acc[0][c] = fmaf(a0, w[c], acc[0][c]);
            acc[1][c] = fmaf(a1, w[c], acc[1][c]);
        }
    }
#pragma unroll
    for (int j = 0; j < 2; ++j) {
        const int n = nb + ln + 32 * j;
        if (n < N_NODES) {
            *(float4*)(h + (size_t)n * HID + c0)     = make_float4(acc[j][0], acc[j][1], acc[j][2], acc[j][3]);
            *(float4*)(h + (size_t)n * HID + c0 + 4) = make_float4(acc[j][4], acc[j][5], acc[j][6], acc[j][7]);
        }
    }
}

// ---------------------------------------------------------------- mean-pool of h (before proj_out)
// batch is sorted: wave-per-chunk register accumulation, flush on graph change.
#define POOL_CHUNK 128
__global__ __launch_bounds__(256) void k_pool(
        const float* __restrict__ h, const int* __restrict__ batch,
        float* __restrict__ sums /*[128][64]*/, float* __restrict__ cnts) {
    const int w = blockIdx.x * 4 + (threadIdx.x >> 6);
    const int lane = threadIdx.x & 63;
    const int n0 = w * POOL_CHUNK;
    if (n0 >= N_NODES) return;
    const int n1 = min(n0 + POOL_CHUNK, N_NODES);
    int cur = batch[n0];
    float acc = 0.0f, cnt = 0.0f;
    for (int n = n0; n < n1; ++n) {
        const int g = batch[n];               // wave-uniform broadcast load
        if (g != cur) {
            atomicAdd(&sums[cur * HID + lane], acc);
            if (lane == 0) atomicAdd(&cnts[cur], cnt);
            acc = 0.0f; cnt = 0.0f; cur = g;
        }
        acc += h[(size_t)n * HID + lane];
        cnt += 1.0f;
    }
    atomicAdd(&sums[cur * HID + lane], acc);
    if (lane == 0) atomicAdd(&cnts[cur], cnt);
}

// ---------------------------------------------------------------- pooled proj_out
// out[g][c] = cnt[g]>0 ? mean[g] @ W_out + b_out : 0   (mean-pool commutes with linear)
__global__ __launch_bounds__(256) void k_pfinal(
        const float* __restrict__ sums, const float* __restrict__ cnts,
        const float* __restrict__ Wo, const float* __restrict__ bo,
        float* __restrict__ out) {
    __shared__ float Wl[HID * OUT_DIM];   // 32 KB
    const int t = threadIdx.x;
    for (int i = t; i < HID * OUT_DIM; i += 256) Wl[i] = Wo[i];
    __syncthreads();
    const int idx = blockIdx.x * 256 + t;
    const int g = idx >> 7;
    const int c = idx & 127;
    const float cnt = cnts[g];
    const float inv = cnt > 0.0f ? 1.0f / cnt : 0.0f;
    float acc = 0.0f;
    for (int k = 0; k < HID; ++k)
        acc = fmaf(sums[g * HID + k], Wl[k * OUT_DIM + c], acc);
    out[idx] = cnt > 0.0f ? acc * inv + bo[c] : 0.0f;
}

// ---------------------------------------------------------------- launch
extern "C" void kernel_launch(void* const* d_in, const int* in_sizes, int n_in,
                              void* d_out, int out_size, void* d_ws, size_t ws_size,
                              hipStream_t stream) {
    const float* x     = (const float*)d_in[0];
    const int*   ei    = (const int*)d_in[1];
    const int*   batch = (const int*)d_in[2];
    const float* W_in  = (const float*)d_in[3];
    const float* b_in  = (const float*)d_in[4];
    const float* W1_0  = (const float*)d_in[5];
    const float* b1_0  = (const float*)d_in[6];
    const float* W2_0  = (const float*)d_in[7];
    const float* b2_0  = (const float*)d_in[8];
    const float* W1_1  = (const float*)d_in[9];
    const float* b1_1  = (const float*)d_in[10];
    const float* W2_1  = (const float*)d_in[11];
    const float* b2_1  = (const float*)d_in[12];
    const float* W_out = (const float*)d_in[13];
    const float* b_out = (const float*)d_in[14];
    float* out = (float*)d_out;

    unsigned int* wsw = (unsigned int*)d_ws;
    int*   deg    = (int*)(wsw + OFF_DEG);
    float* sums   = (float*)(wsw + OFF_SUMS);
    float* cnts   = (float*)(wsw + OFF_CNT);
    int*   rowptr = (int*)(wsw + OFF_ROWPTR);
    int*   cursor = (int*)(wsw + OFF_CURSOR);
    int*   srcl   = (int*)(wsw + OFF_SRCL);
    float* bufA   = (float*)(wsw + OFF_BUFA);
    float* bufB   = (float*)(wsw + OFF_BUFB);

    const int eblocks = (N_EDGES + 255) / 256;           // 3125
    const int pi_blocks = (N_NODES + 63) / 64;           // 782
    const int mlp_blocks = (N_NODES + 127) / 128;        // 391
    const int ag_blocks = N_NODES / 16;                  // 3125 (exact)
    const int pool_blocks = (N_NODES + 4 * POOL_CHUNK - 1) / (4 * POOL_CHUNK);  // 98

    k_zero<<<512, 256, 0, stream>>>(wsw, ZERO_WORDS);
    k_hist<<<eblocks, 256, 0, stream>>>(ei, deg);
    k_scan<<<1, 1024, 0, stream>>>(deg, rowptr, cursor);
    k_fill<<<eblocks, 256, 0, stream>>>(ei, cursor, srcl);

    k_proj_in<<<pi_blocks, 256, 0, stream>>>(x, W_in, b_in, bufA);
    // conv 0
    k_aggr<<<ag_blocks, 256, 0, stream>>>(bufA, rowptr, srcl, bufB);
    k_mlp<<<mlp_blocks, 256, 0, stream>>>(bufB, W1_0, b1_0, W2_0, b2_0, bufA);
    // conv 1
    k_aggr<<<ag_blocks, 256, 0, stream>>>(bufA, rowptr, srcl, bufB);
    k_mlp<<<mlp_blocks, 256, 0, stream>>>(bufB, W1_1, b1_1, W2_1, b2_1, bufA);
    // pool then tiny proj_out
    k_pool<<<pool_blocks, 256, 0, stream>>>(bufA, batch, sums, cnts);
    k_pfinal<<<(N_GRAPHS * OUT_DIM) / 256, 256, 0, stream>>>(sums, cnts, W_out, b_out, out);
}

// Round 4
// 362.645 us; speedup vs baseline: 4.9452x; 1.2806x over previous
//
#include <hip/hip_runtime.h>

// Problem constants (fixed by the reference)
#define N_NODES   50000
#define N_EDGES   800000
#define IN_DIM    128
#define HID       64
#define OUT_DIM   128
#define N_GRAPHS  128

// Workspace layout in 4-byte words.
// [deg|sums|cnts] contiguous -> one zero-fill covers all three.
#define OFF_DEG     0                           // int[50000]
#define OFF_SUMS    50000                       // float[128*64] pooled-h sums
#define OFF_CNT     58192                       // float[128]
#define ZERO_WORDS  58320
#define OFF_ROWPTR  58320                       // int[50001]
#define OFF_CURSOR  108321                      // int[50000]
#define OFF_SRCL    158336                      // int[800000]   (16-aligned)
#define OFF_BUFA    958336                      // float[3,200,000]
#define OFF_BUFB    4158336                     // float[3,200,000]
// scan partials live in the tail of BUFB (bufB is first written later, by k_aggr)
#define SCAN_BLOCKS 196

// ---------------------------------------------------------------- zero fill
__global__ void k_zero(unsigned int* __restrict__ p, int n) {
    int i = blockIdx.x * blockDim.x + threadIdx.x;
    int stride = gridDim.x * blockDim.x;
    for (; i < n; i += stride) p[i] = 0u;
}

// ---------------------------------------------------------------- CSR build
__global__ __launch_bounds__(256) void k_hist(const int* __restrict__ ei,
                                              int* __restrict__ deg) {
    const int e = blockIdx.x * blockDim.x + threadIdx.x;
    if (e < N_EDGES) atomicAdd(&deg[ei[N_EDGES + e]], 1);
}

// per-block degree sums -> partial[b]
__global__ __launch_bounds__(256) void k_scan1(const int* __restrict__ deg,
                                               int* __restrict__ partial) {
    const int n = blockIdx.x * 256 + threadIdx.x;
    int v = (n < N_NODES) ? deg[n] : 0;
#pragma unroll
    for (int m = 32; m; m >>= 1) v += __shfl_xor(v, m, 64);
    __shared__ int ws[4];
    if ((threadIdx.x & 63) == 0) ws[threadIdx.x >> 6] = v;
    __syncthreads();
    if (threadIdx.x == 0) partial[blockIdx.x] = ws[0] + ws[1] + ws[2] + ws[3];
}

// block-local exclusive scan + cross-block offset (reduce partial[0..b)) -> rowptr/cursor
__global__ __launch_bounds__(256) void k_scan2(const int* __restrict__ deg,
                                               const int* __restrict__ partial,
                                               int* __restrict__ rowptr,
                                               int* __restrict__ cursor) {
    const int t = threadIdx.x;
    const int lane = t & 63;
    const int wv = t >> 6;
    __shared__ int pws[4];
    __shared__ int wtot[4];

    // block offset = sum of partial[0..blockIdx.x)
    int po = 0;
    for (int i = t; i < blockIdx.x; i += 256) po += partial[i];
#pragma unroll
    for (int m = 32; m; m >>= 1) po += __shfl_xor(po, m, 64);
    if (lane == 0) pws[wv] = po;

    // wave-level inclusive scan of this thread's degree
    const int n = blockIdx.x * 256 + t;
    const int d = (n < N_NODES) ? deg[n] : 0;
    int incl = d;
#pragma unroll
    for (int off = 1; off < 64; off <<= 1) {
        const int u = __shfl_up(incl, off, 64);
        if (lane >= off) incl += u;
    }
    if (lane == 63) wtot[wv] = incl;
    __syncthreads();

    const int blockoff = pws[0] + pws[1] + pws[2] + pws[3];
    int woff = 0;
#pragma unroll
    for (int i = 0; i < 4; ++i) woff += (i < wv) ? wtot[i] : 0;
    const int excl = blockoff + woff + incl - d;
    if (n <= N_NODES) rowptr[n] = excl;   // n==N_NODES thread writes total (=N_EDGES)
    if (n < N_NODES)  cursor[n] = excl;
}

__global__ __launch_bounds__(256) void k_fill(const int* __restrict__ ei,
                                              int* __restrict__ cursor,
                                              int* __restrict__ srclist) {
    const int e = blockIdx.x * blockDim.x + threadIdx.x;
    if (e >= N_EDGES) return;
    const int dst = ei[N_EDGES + e];
    const int pos = atomicAdd(&cursor[dst], 1);
    srclist[pos] = ei[e];
}

// ---------------------------------------------------------------- aggregation (gather)
// v[n] = h[n] + sum_{src in in(n)} h[src]
// Wave = 4 nodes; 16-lane group per node; lane q = float4 chunk of the row.
__global__ __launch_bounds__(256) void k_aggr(
        const float* __restrict__ h,
        const int* __restrict__ rowptr, const int* __restrict__ srclist,
        float* __restrict__ v) {
    const int t = threadIdx.x;
    const int wv = t >> 6;            // wave in block (0..3)
    const int lane = t & 63;
    const int g = lane >> 4;          // node group (0..3)
    const int q = lane & 15;          // float4 chunk (0..15)
    const int node = blockIdx.x * 16 + wv * 4 + g;   // N_NODES = 3125*16 exact

    const int beg = rowptr[node];
    const int end = rowptr[node + 1];

    float4 acc = *(const float4*)(h + (size_t)node * HID + q * 4);
    int e = beg;
    for (; e + 4 <= end; e += 4) {
        const int s0 = srclist[e];
        const int s1 = srclist[e + 1];
        const int s2 = srclist[e + 2];
        const int s3 = srclist[e + 3];
        const float4 a0 = *(const float4*)(h + (size_t)s0 * HID + q * 4);
        const float4 a1 = *(const float4*)(h + (size_t)s1 * HID + q * 4);
        const float4 a2 = *(const float4*)(h + (size_t)s2 * HID + q * 4);
        const float4 a3 = *(const float4*)(h + (size_t)s3 * HID + q * 4);
        acc.x += a0.x + a1.x + a2.x + a3.x;
        acc.y += a0.y + a1.y + a2.y + a3.y;
        acc.z += a0.z + a1.z + a2.z + a3.z;
        acc.w += a0.w + a1.w + a2.w + a3.w;
    }
    for (; e < end; ++e) {
        const int s = srclist[e];
        const float4 a = *(const float4*)(h + (size_t)s * HID + q * 4);
        acc.x += a.x; acc.y += a.y; acc.z += a.z; acc.w += a.w;
    }
    *(float4*)(v + (size_t)node * HID + q * 4) = acc;
}

// ---------------------------------------------------------------- GIN MLP (GEMM-tiled)
// hout = relu( relu(v @ W1 + b1) @ W2 + b2 ), 128 nodes per block,
// thread = 4 nodes x 8 cols. Activations in LDS stride 65 (==1 mod 32).
#define S_A 65
__global__ __launch_bounds__(256) void k_mlp(
        const float* __restrict__ v,
        const float* __restrict__ W1, const float* __restrict__ b1,
        const float* __restrict__ W2, const float* __restrict__ b2,
        float* __restrict__ hout) {
    __shared__ float A[128 * S_A];          // 33.3 KB (reused for u)
    __shared__ float Wl[2 * HID * HID];     // 32 KB
    const int t = threadIdx.x;
    for (int i = t; i < HID * HID; i += 256) {
        Wl[i] = W1[i];
        Wl[HID * HID + i] = W2[i];
    }
    const int nb = blockIdx.x * 128;
    // stage v tile -> A[n][k]
    for (int i = t; i < 128 * (HID / 4); i += 256) {
        const int n = i >> 4;
        const int k4 = (i & 15) * 4;
        float4 val = make_float4(0.f, 0.f, 0.f, 0.f);
        if (nb + n < N_NODES)
            val = *(const float4*)(v + (size_t)(nb + n) * HID + k4);
        float* dst = &A[n * S_A + k4];
        dst[0] = val.x; dst[1] = val.y; dst[2] = val.z; dst[3] = val.w;
    }
    __syncthreads();

    const int ln = t & 31;                // node lane: nodes ln+32j
    const int c0 = (t >> 5) * 8;          // col octet
    float bb1[8], bb2[8];
#pragma unroll
    for (int c = 0; c < 8; ++c) { bb1[c] = b1[c0 + c]; bb2[c] = b2[c0 + c]; }

    float acc[4][8];
    // ---- layer 1
#pragma unroll
    for (int j = 0; j < 4; ++j)
#pragma unroll
        for (int c = 0; c < 8; ++c) acc[j][c] = bb1[c];
    for (int k = 0; k < HID; ++k) {
        float a[4];
#pragma unroll
        for (int j = 0; j < 4; ++j) a[j] = A[(ln + 32 * j) * S_A + k];
        const float4 wA = *(const float4*)&Wl[k * HID + c0];
        const float4 wB = *(const float4*)&Wl[k * HID + c0 + 4];
        const float w[8] = {wA.x, wA.y, wA.z, wA.w, wB.x, wB.y, wB.z, wB.w};
#pragma unroll
        for (int j = 0; j < 4; ++j)
#pragma unroll
            for (int c = 0; c < 8; ++c)
                acc[j][c] = fmaf(a[j], w[c], acc[j][c]);
    }
    __syncthreads();  // all layer-1 reads of A done
    // write u = relu(acc) into A[n][c]
#pragma unroll
    for (int j = 0; j < 4; ++j) {
        float* dst = &A[(ln + 32 * j) * S_A + c0];
#pragma unroll
        for (int c = 0; c < 8; ++c) dst[c] = fmaxf(acc[j][c], 0.0f);
    }
    __syncthreads();

    // ---- layer 2
#pragma unroll
    for (int j = 0; j < 4; ++j)
#pragma unroll
        for (int c = 0; c < 8; ++c) acc[j][c] = bb2[c];
    for (int k = 0; k < HID; ++k) {
        float a[4];
#pragma unroll
        for (int j = 0; j < 4; ++j) a[j] = A[(ln + 32 * j) * S_A + k];
        const float4 wA = *(const float4*)&Wl[HID * HID + k * HID + c0];
        const float4 wB = *(const float4*)&Wl[HID * HID + k * HID + c0 + 4];
        const float w[8] = {wA.x, wA.y, wA.z, wA.w, wB.x, wB.y, wB.z, wB.w};
#pragma unroll
        for (int j = 0; j < 4; ++j)
#pragma unroll
            for (int c = 0; c < 8; ++c)
                acc[j][c] = fmaf(a[j], w[c], acc[j][c]);
    }
    // relu + store
#pragma unroll
    for (int j = 0; j < 4; ++j) {
        const int n = nb + ln + 32 * j;
        if (n < N_NODES) {
            float4 o0, o1;
            o0.x = fmaxf(acc[j][0], 0.f); o0.y = fmaxf(acc[j][1], 0.f);
            o0.z = fmaxf(acc[j][2], 0.f); o0.w = fmaxf(acc[j][3], 0.f);
            o1.x = fmaxf(acc[j][4], 0.f); o1.y = fmaxf(acc[j][5], 0.f);
            o1.z = fmaxf(acc[j][6], 0.f); o1.w = fmaxf(acc[j][7], 0.f);
            *(float4*)(hout + (size_t)n * HID + c0) = o0;
            *(float4*)(hout + (size_t)n * HID + c0 + 4) = o1;
        }
    }
}

// ---------------------------------------------------------------- proj_in (GEMM-tiled, K=128)
#define S_X 129
__global__ __launch_bounds__(256) void k_proj_in(
        const float* __restrict__ x, const float* __restrict__ W,
        const float* __restrict__ b, float* __restrict__ h) {
    __shared__ float A[64 * S_X];           // 33 KB
    __shared__ float Wl[IN_DIM * HID];      // 32 KB
    const int t = threadIdx.x;
    for (int i = t; i < IN_DIM * HID; i += 256) Wl[i] = W[i];
    const int nb = blockIdx.x * 64;
    for (int i = t; i < 64 * (IN_DIM / 4); i += 256) {   // 2048 chunks
        const int n = i >> 5;
        const int k4 = (i & 31) * 4;
        float4 val = make_float4(0.f, 0.f, 0.f, 0.f);
        if (nb + n < N_NODES)
            val = *(const float4*)(x + (size_t)(nb + n) * IN_DIM + k4);
        float* dst = &A[n * S_X + k4];
        dst[0] = val.x; dst[1] = val.y; dst[2] = val.z; dst[3] = val.w;
    }
    __syncthreads();

    const int ln = t & 31;                // nodes ln, ln+32
    const int c0 = (t >> 5) * 8;
    float acc[2][8];
#pragma unroll
    for (int j = 0; j < 2; ++j)
#pragma unroll
        for (int c = 0; c < 8; ++c) acc[j][c] = b[c0 + c];
    for (int k = 0; k < IN_DIM; ++k) {
        const float a0 = A[ln * S_X + k];
        const float a1 = A[(ln + 32) * S_X + k];
        const float4 wA = *(const float4*)&Wl[k * HID + c0];
        const float4 wB = *(const float4*)&Wl[k * HID + c0 + 4];
        const float w[8] = {wA.x, wA.y, wA.z, wA.w, wB.x, wB.y, wB.z, wB.w};
#pragma unroll
        for (int c = 0; c < 8; ++c) {
            acc[0][c] = fmaf(a0, w[c], acc[0][c]);
            acc[1][c] = fmaf(a1, w[c], acc[1][c]);
        }
    }
#pragma unroll
    for (int j = 0; j < 2; ++j) {
        const int n = nb + ln + 32 * j;
        if (n < N_NODES) {
            *(float4*)(h + (size_t)n * HID + c0)     = make_float4(acc[j][0], acc[j][1], acc[j][2], acc[j][3]);
            *(float4*)(h + (size_t)n * HID + c0 + 4) = make_float4(acc[j][4], acc[j][5], acc[j][6], acc[j][7]);
        }
    }
}

// ---------------------------------------------------------------- mean-pool of h (before proj_out)
#define POOL_CHUNK 128
__global__ __launch_bounds__(256) void k_pool(
        const float* __restrict__ h, const int* __restrict__ batch,
        float* __restrict__ sums /*[128][64]*/, float* __restrict__ cnts) {
    const int w = blockIdx.x * 4 + (threadIdx.x >> 6);
    const int lane = threadIdx.x & 63;
    const int n0 = w * POOL_CHUNK;
    if (n0 >= N_NODES) return;
    const int n1 = min(n0 + POOL_CHUNK, N_NODES);
    int cur = batch[n0];
    float acc = 0.0f, cnt = 0.0f;
    for (int n = n0; n < n1; ++n) {
        const int g = batch[n];               // wave-uniform broadcast load
        if (g != cur) {
            atomicAdd(&sums[cur * HID + lane], acc);
            if (lane == 0) atomicAdd(&cnts[cur], cnt);
            acc = 0.0f; cnt = 0.0f; cur = g;
        }
        acc += h[(size_t)n * HID + lane];
        cnt += 1.0f;
    }
    atomicAdd(&sums[cur * HID + lane], acc);
    if (lane == 0) atomicAdd(&cnts[cur], cnt);
}

// ---------------------------------------------------------------- pooled proj_out
__global__ __launch_bounds__(256) void k_pfinal(
        const float* __restrict__ sums, const float* __restrict__ cnts,
        const float* __restrict__ Wo, const float* __restrict__ bo,
        float* __restrict__ out) {
    __shared__ float Wl[HID * OUT_DIM];   // 32 KB
    const int t = threadIdx.x;
    for (int i = t; i < HID * OUT_DIM; i += 256) Wl[i] = Wo[i];
    __syncthreads();
    const int idx = blockIdx.x * 256 + t;
    const int g = idx >> 7;
    const int c = idx & 127;
    const float cnt = cnts[g];
    const float inv = cnt > 0.0f ? 1.0f / cnt : 0.0f;
    float acc = 0.0f;
    for (int k = 0; k < HID; ++k)
        acc = fmaf(sums[g * HID + k], Wl[k * OUT_DIM + c], acc);
    out[idx] = cnt > 0.0f ? acc * inv + bo[c] : 0.0f;
}

// ---------------------------------------------------------------- launch
extern "C" void kernel_launch(void* const* d_in, const int* in_sizes, int n_in,
                              void* d_out, int out_size, void* d_ws, size_t ws_size,
                              hipStream_t stream) {
    const float* x     = (const float*)d_in[0];
    const int*   ei    = (const int*)d_in[1];
    const int*   batch = (const int*)d_in[2];
    const float* W_in  = (const float*)d_in[3];
    const float* b_in  = (const float*)d_in[4];
    const float* W1_0  = (const float*)d_in[5];
    const float* b1_0  = (const float*)d_in[6];
    const float* W2_0  = (const float*)d_in[7];
    const float* b2_0  = (const float*)d_in[8];
    const float* W1_1  = (const float*)d_in[9];
    const float* b1_1  = (const float*)d_in[10];
    const float* W2_1  = (const float*)d_in[11];
    const float* b2_1  = (const float*)d_in[12];
    const float* W_out = (const float*)d_in[13];
    const float* b_out = (const float*)d_in[14];
    float* out = (float*)d_out;

    unsigned int* wsw = (unsigned int*)d_ws;
    int*   deg    = (int*)(wsw + OFF_DEG);
    float* sums   = (float*)(wsw + OFF_SUMS);
    float* cnts   = (float*)(wsw + OFF_CNT);
    int*   rowptr = (int*)(wsw + OFF_ROWPTR);
    int*   cursor = (int*)(wsw + OFF_CURSOR);
    int*   srcl   = (int*)(wsw + OFF_SRCL);
    float* bufA   = (float*)(wsw + OFF_BUFA);
    float* bufB   = (float*)(wsw + OFF_BUFB);
    // scan partials in the tail of bufB (bufB first written later, by k_aggr)
    int*   partial = (int*)(bufB + 3200000 - 256);

    const int eblocks = (N_EDGES + 255) / 256;           // 3125
    const int pi_blocks = (N_NODES + 63) / 64;           // 782
    const int mlp_blocks = (N_NODES + 127) / 128;        // 391
    const int ag_blocks = N_NODES / 16;                  // 3125 (exact)
    const int pool_blocks = (N_NODES + 4 * POOL_CHUNK - 1) / (4 * POOL_CHUNK);  // 98

    k_zero<<<512, 256, 0, stream>>>(wsw, ZERO_WORDS);
    k_hist<<<eblocks, 256, 0, stream>>>(ei, deg);
    k_scan1<<<SCAN_BLOCKS, 256, 0, stream>>>(deg, partial);
    k_scan2<<<SCAN_BLOCKS, 256, 0, stream>>>(deg, partial, rowptr, cursor);
    k_fill<<<eblocks, 256, 0, stream>>>(ei, cursor, srcl);

    k_proj_in<<<pi_blocks, 256, 0, stream>>>(x, W_in, b_in, bufA);
    // conv 0
    k_aggr<<<ag_blocks, 256, 0, stream>>>(bufA, rowptr, srcl, bufB);
    k_mlp<<<mlp_blocks, 256, 0, stream>>>(bufB, W1_0, b1_0, W2_0, b2_0, bufA);
    // conv 1
    k_aggr<<<ag_blocks, 256, 0, stream>>>(bufA, rowptr, srcl, bufB);
    k_mlp<<<mlp_blocks, 256, 0, stream>>>(bufB, W1_1, b1_1, W2_1, b2_1, bufA);
    // pool then tiny proj_out
    k_pool<<<pool_blocks, 256, 0, stream>>>(bufA, batch, sums, cnts);
    k_pfinal<<<(N_GRAPHS * OUT_DIM) / 256, 256, 0, stream>>>(sums, cnts, W_out, b_out, out);
}

// Round 5
// 299.959 us; speedup vs baseline: 5.9787x; 1.2090x over previous
//
#include <hip/hip_runtime.h>
#include <hip/hip_fp16.h>

// Problem constants (fixed by the reference)
#define N_NODES   50000
#define N_EDGES   800000
#define IN_DIM    128
#define HID       64
#define OUT_DIM   128
#define N_GRAPHS  128

#define NBKT      196        // ceil(50000/256) coarse dst-buckets
#define BSTRIDE   5120       // slots/bucket (mean 4096, 16-sigma margin)
#define CAP       40         // LDS staging depth per bucket (pass A)

// Workspace layout in 4-byte words. [gcur|sums|cnts] contiguous -> one zero-fill.
#define OFF_GCUR   0                    // int[196]
#define OFF_SUMS   196                  // float[128*64]
#define OFF_CNT    8388                 // float[128]
#define ZERO_WORDS 8516
#define OFF_ROWPTR 8516                 // int[50001]
#define OFF_HH     58520                // __half[50000*64] = 1,600,000 words
#define OFF_V      1658520              // float[3,200,000]; epairs uint32[196*5120] aliases here
#define OFF_SRCL   4858520              // int[800000]
// end = 5,658,520 words = 22.6 MB

// ---------------------------------------------------------------- zero fill
__global__ void k_zero(unsigned int* __restrict__ p, int n) {
    int i = blockIdx.x * blockDim.x + threadIdx.x;
    int stride = gridDim.x * blockDim.x;
    for (; i < n; i += stride) p[i] = 0u;
}

// ---------------------------------------------------------------- pass A: coarse bucket scatter
// epairs[b*BSTRIDE ...] <- packed (src | dst<<16) for all edges with dst>>8 == b.
// LDS staging, flushes in 16-uint (64B) aligned chunks -> full-line HBM writes.
__global__ __launch_bounds__(256) void k_bucket(const int* __restrict__ ei,
                                                int* __restrict__ gcur,
                                                unsigned int* __restrict__ epairs) {
    __shared__ int lcnt[NBKT];
    __shared__ unsigned int stage[NBKT * CAP];   // 31.4 KB
    const int t = threadIdx.x;
    for (int i = t; i < NBKT; i += 256) lcnt[i] = 0;
    __syncthreads();
    for (int e0 = blockIdx.x * 256; e0 < N_EDGES; e0 += gridDim.x * 256) {
        const int e = e0 + t;
        if (e < N_EDGES) {
            const unsigned int src = (unsigned int)ei[e];
            const unsigned int dst = (unsigned int)ei[N_EDGES + e];
            const int b = dst >> 8;
            const unsigned int pk = src | (dst << 16);   // both < 2^16
            const int pos = atomicAdd(&lcnt[b], 1);
            if (pos < CAP) stage[b * CAP + pos] = pk;
            else {  // rare overflow: direct scattered write
                const int gp = atomicAdd(&gcur[b], 1);
                epairs[b * BSTRIDE + gp] = pk;
            }
        }
        __syncthreads();
        if (t < NBKT) {
            int n = lcnt[t]; if (n > CAP) n = CAP;
            if (n >= 16) {
                const int f = n & ~15;               // 16 or 32 -> 64B-aligned chunks
                const int base = atomicAdd(&gcur[t], f);
                for (int i = 0; i < f; ++i)
                    epairs[t * BSTRIDE + base + i] = stage[t * CAP + i];
                for (int i = 0; i < n - f; ++i)      // move remainder to front
                    stage[t * CAP + i] = stage[t * CAP + f + i];
                lcnt[t] = n - f;
            } else {
                lcnt[t] = n;
            }
        }
        __syncthreads();
    }
    // drain remainders
    if (t < NBKT) {
        const int n = lcnt[t];
        if (n > 0) {
            const int base = atomicAdd(&gcur[t], n);
            for (int i = 0; i < n; ++i)
                epairs[t * BSTRIDE + base + i] = stage[t * CAP + i];
        }
    }
}

// ---------------------------------------------------------------- pass B: per-bucket CSR in LDS
// Block b: fine-sort bucket b's edges by dst in LDS; write srclist (coalesced,
// contiguous region) + rowptr for its 256 nodes.
__global__ __launch_bounds__(256) void k_csr(const int* __restrict__ gcur,
                                             const unsigned int* __restrict__ epairs,
                                             int* __restrict__ rowptr,
                                             int* __restrict__ srclist) {
    __shared__ int lhist[256];
    __shared__ int lcur[256];
    __shared__ int lsrc[BSTRIDE];     // 20.5 KB
    __shared__ int pws[4], wtot[4];
    const int b = blockIdx.x;
    const int t = threadIdx.x;
    const int lane = t & 63, wv = t >> 6;

    // base = sum gcur[0..b)
    int po = 0;
    for (int j = t; j < b; j += 256) po += gcur[j];
#pragma unroll
    for (int m = 32; m; m >>= 1) po += __shfl_xor(po, m, 64);
    if (lane == 0) pws[wv] = po;
    lhist[t] = 0;
    __syncthreads();
    const int base = pws[0] + pws[1] + pws[2] + pws[3];
    const int cnt = gcur[b];

    // local histogram over the bucket's 256 nodes
    for (int i = t; i < cnt; i += 256)
        atomicAdd(&lhist[(epairs[b * BSTRIDE + i] >> 16) & 255], 1);
    __syncthreads();

    // exclusive scan of lhist[256]
    const int d = lhist[t];
    int incl = d;
#pragma unroll
    for (int off = 1; off < 64; off <<= 1) {
        const int u = __shfl_up(incl, off, 64);
        if (lane >= off) incl += u;
    }
    if (lane == 63) wtot[wv] = incl;
    __syncthreads();
    int woff = 0;
#pragma unroll
    for (int i = 0; i < 4; ++i) woff += (i < wv) ? wtot[i] : 0;
    const int excl = woff + incl - d;
    lcur[t] = excl;
    const int node = b * 256 + t;
    if (node < N_NODES) rowptr[node] = base + excl;
    if (b == NBKT - 1 && t == 0) rowptr[N_NODES] = base + cnt;  // == N_EDGES
    __syncthreads();

    // scatter src into fine order (LDS)
    for (int i = t; i < cnt; i += 256) {
        const unsigned int u = epairs[b * BSTRIDE + i];
        const int pos = atomicAdd(&lcur[(u >> 16) & 255], 1);
        lsrc[pos] = (int)(u & 0xFFFFu);
    }
    __syncthreads();
    // coalesced contiguous writeout
    for (int i = t; i < cnt; i += 256) srclist[base + i] = lsrc[i];
}

// ---------------------------------------------------------------- proj_in (fp16 output)
#define S_X 129
union H8 { float4 f4; __half2 h[4]; };
__global__ __launch_bounds__(256) void k_proj_in(
        const float* __restrict__ x, const float* __restrict__ W,
        const float* __restrict__ b, __half* __restrict__ hH) {
    __shared__ float A[64 * S_X];           // 33 KB
    __shared__ float Wl[IN_DIM * HID];      // 32 KB
    const int t = threadIdx.x;
    for (int i = t; i < IN_DIM * HID; i += 256) Wl[i] = W[i];
    const int nb = blockIdx.x * 64;
    for (int i = t; i < 64 * (IN_DIM / 4); i += 256) {
        const int n = i >> 5;
        const int k4 = (i & 31) * 4;
        float4 val = make_float4(0.f, 0.f, 0.f, 0.f);
        if (nb + n < N_NODES)
            val = *(const float4*)(x + (size_t)(nb + n) * IN_DIM + k4);
        float* dst = &A[n * S_X + k4];
        dst[0] = val.x; dst[1] = val.y; dst[2] = val.z; dst[3] = val.w;
    }
    __syncthreads();

    const int ln = t & 31;
    const int c0 = (t >> 5) * 8;
    float acc[2][8];
#pragma unroll
    for (int j = 0; j < 2; ++j)
#pragma unroll
        for (int c = 0; c < 8; ++c) acc[j][c] = b[c0 + c];
    for (int k = 0; k < IN_DIM; ++k) {
        const float a0 = A[ln * S_X + k];
        const float a1 = A[(ln + 32) * S_X + k];
        const float4 wA = *(const float4*)&Wl[k * HID + c0];
        const float4 wB = *(const float4*)&Wl[k * HID + c0 + 4];
        const float w[8] = {wA.x, wA.y, wA.z, wA.w, wB.x, wB.y, wB.z, wB.w};
#pragma unroll
        for (int c = 0; c < 8; ++c) {
            acc[0][c] = fmaf(a0, w[c], acc[0][c]);
            acc[1][c] = fmaf(a1, w[c], acc[1][c]);
        }
    }
#pragma unroll
    for (int j = 0; j < 2; ++j) {
        const int n = nb + ln + 32 * j;
        if (n < N_NODES) {
            H8 o;
#pragma unroll
            for (int c = 0; c < 4; ++c)
                o.h[c] = __floats2half2_rn(acc[j][2 * c], acc[j][2 * c + 1]);
            *(float4*)(hH + (size_t)n * HID + c0) = o.f4;   // 16B aligned (c0 mult of 8)
        }
    }
}

// ---------------------------------------------------------------- aggregation (fp16 gather, fp32 acc)
__device__ inline void acc_h4(float4& a, const float2 r) {
    const __half2 h0 = *(const __half2*)&r.x;
    const __half2 h1 = *(const __half2*)&r.y;
    const float2 f0 = __half22float2(h0);
    const float2 f1 = __half22float2(h1);
    a.x += f0.x; a.y += f0.y; a.z += f1.x; a.w += f1.y;
}

__global__ __launch_bounds__(256) void k_aggr(
        const __half* __restrict__ hH,
        const int* __restrict__ rowptr, const int* __restrict__ srclist,
        float* __restrict__ v) {
    const int t = threadIdx.x;
    const int wv = t >> 6;
    const int lane = t & 63;
    const int g = lane >> 4;          // node group (0..3)
    const int q = lane & 15;          // 4-elem chunk (0..15)
    const int node = blockIdx.x * 16 + wv * 4 + g;   // N_NODES = 3125*16 exact

    const int beg = rowptr[node];
    const int end = rowptr[node + 1];

    float4 acc = make_float4(0.f, 0.f, 0.f, 0.f);
    acc_h4(acc, *(const float2*)(hH + (size_t)node * HID + q * 4));   // self

    int e = beg;
    for (; e + 4 <= end; e += 4) {
        const int s0 = srclist[e];
        const int s1 = srclist[e + 1];
        const int s2 = srclist[e + 2];
        const int s3 = srclist[e + 3];
        const float2 r0 = *(const float2*)(hH + (size_t)s0 * HID + q * 4);
        const float2 r1 = *(const float2*)(hH + (size_t)s1 * HID + q * 4);
        const float2 r2 = *(const float2*)(hH + (size_t)s2 * HID + q * 4);
        const float2 r3 = *(const float2*)(hH + (size_t)s3 * HID + q * 4);
        acc_h4(acc, r0); acc_h4(acc, r1); acc_h4(acc, r2); acc_h4(acc, r3);
    }
    for (; e < end; ++e)
        acc_h4(acc, *(const float2*)(hH + (size_t)srclist[e] * HID + q * 4));

    *(float4*)(v + (size_t)node * HID + q * 4) = acc;
}

// ---------------------------------------------------------------- GIN MLP (fp32 in, fp16 out)
#define S_A 65
__global__ __launch_bounds__(256) void k_mlp(
        const float* __restrict__ v,
        const float* __restrict__ W1, const float* __restrict__ b1,
        const float* __restrict__ W2, const float* __restrict__ b2,
        __half* __restrict__ hH) {
    __shared__ float A[128 * S_A];          // 33.3 KB
    __shared__ float Wl[2 * HID * HID];     // 32 KB
    const int t = threadIdx.x;
    for (int i = t; i < HID * HID; i += 256) {
        Wl[i] = W1[i];
        Wl[HID * HID + i] = W2[i];
    }
    const int nb = blockIdx.x * 128;
    for (int i = t; i < 128 * (HID / 4); i += 256) {
        const int n = i >> 4;
        const int k4 = (i & 15) * 4;
        float4 val = make_float4(0.f, 0.f, 0.f, 0.f);
        if (nb + n < N_NODES)
            val = *(const float4*)(v + (size_t)(nb + n) * HID + k4);
        float* dst = &A[n * S_A + k4];
        dst[0] = val.x; dst[1] = val.y; dst[2] = val.z; dst[3] = val.w;
    }
    __syncthreads();

    const int ln = t & 31;
    const int c0 = (t >> 5) * 8;
    float bb1[8], bb2[8];
#pragma unroll
    for (int c = 0; c < 8; ++c) { bb1[c] = b1[c0 + c]; bb2[c] = b2[c0 + c]; }

    float acc[4][8];
#pragma unroll
    for (int j = 0; j < 4; ++j)
#pragma unroll
        for (int c = 0; c < 8; ++c) acc[j][c] = bb1[c];
    for (int k = 0; k < HID; ++k) {
        float a[4];
#pragma unroll
        for (int j = 0; j < 4; ++j) a[j] = A[(ln + 32 * j) * S_A + k];
        const float4 wA = *(const float4*)&Wl[k * HID + c0];
        const float4 wB = *(const float4*)&Wl[k * HID + c0 + 4];
        const float w[8] = {wA.x, wA.y, wA.z, wA.w, wB.x, wB.y, wB.z, wB.w};
#pragma unroll
        for (int j = 0; j < 4; ++j)
#pragma unroll
            for (int c = 0; c < 8; ++c)
                acc[j][c] = fmaf(a[j], w[c], acc[j][c]);
    }
    __syncthreads();
#pragma unroll
    for (int j = 0; j < 4; ++j) {
        float* dst = &A[(ln + 32 * j) * S_A + c0];
#pragma unroll
        for (int c = 0; c < 8; ++c) dst[c] = fmaxf(acc[j][c], 0.0f);
    }
    __syncthreads();

#pragma unroll
    for (int j = 0; j < 4; ++j)
#pragma unroll
        for (int c = 0; c < 8; ++c) acc[j][c] = bb2[c];
    for (int k = 0; k < HID; ++k) {
        float a[4];
#pragma unroll
        for (int j = 0; j < 4; ++j) a[j] = A[(ln + 32 * j) * S_A + k];
        const float4 wA = *(const float4*)&Wl[HID * HID + k * HID + c0];
        const float4 wB = *(const float4*)&Wl[HID * HID + k * HID + c0 + 4];
        const float w[8] = {wA.x, wA.y, wA.z, wA.w, wB.x, wB.y, wB.z, wB.w};
#pragma unroll
        for (int j = 0; j < 4; ++j)
#pragma unroll
            for (int c = 0; c < 8; ++c)
                acc[j][c] = fmaf(a[j], w[c], acc[j][c]);
    }
#pragma unroll
    for (int j = 0; j < 4; ++j) {
        const int n = nb + ln + 32 * j;
        if (n < N_NODES) {
            H8 o;
#pragma unroll
            for (int c = 0; c < 4; ++c)
                o.h[c] = __floats2half2_rn(fmaxf(acc[j][2 * c], 0.f),
                                           fmaxf(acc[j][2 * c + 1], 0.f));
            *(float4*)(hH + (size_t)n * HID + c0) = o.f4;
        }
    }
}

// ---------------------------------------------------------------- mean-pool of h (fp16 read)
#define POOL_CHUNK 128
__global__ __launch_bounds__(256) void k_pool(
        const __half* __restrict__ hH, const int* __restrict__ batch,
        float* __restrict__ sums /*[128][64]*/, float* __restrict__ cnts) {
    const int w = blockIdx.x * 4 + (threadIdx.x >> 6);
    const int lane = threadIdx.x & 63;
    const int n0 = w * POOL_CHUNK;
    if (n0 >= N_NODES) return;
    const int n1 = min(n0 + POOL_CHUNK, N_NODES);
    int cur = batch[n0];
    float acc = 0.0f, cnt = 0.0f;
    for (int n = n0; n < n1; ++n) {
        const int g = batch[n];
        if (g != cur) {
            atomicAdd(&sums[cur * HID + lane], acc);
            if (lane == 0) atomicAdd(&cnts[cur], cnt);
            acc = 0.0f; cnt = 0.0f; cur = g;
        }
        acc += __half2float(hH[(size_t)n * HID + lane]);
        cnt += 1.0f;
    }
    atomicAdd(&sums[cur * HID + lane], acc);
    if (lane == 0) atomicAdd(&cnts[cur], cnt);
}

// ---------------------------------------------------------------- pooled proj_out
__global__ __launch_bounds__(256) void k_pfinal(
        const float* __restrict__ sums, const float* __restrict__ cnts,
        const float* __restrict__ Wo, const float* __restrict__ bo,
        float* __restrict__ out) {
    __shared__ float Wl[HID * OUT_DIM];   // 32 KB
    const int t = threadIdx.x;
    for (int i = t; i < HID * OUT_DIM; i += 256) Wl[i] = Wo[i];
    __syncthreads();
    const int idx = blockIdx.x * 256 + t;
    const int g = idx >> 7;
    const int c = idx & 127;
    const float cnt = cnts[g];
    const float inv = cnt > 0.0f ? 1.0f / cnt : 0.0f;
    float acc = 0.0f;
    for (int k = 0; k < HID; ++k)
        acc = fmaf(sums[g * HID + k], Wl[k * OUT_DIM + c], acc);
    out[idx] = cnt > 0.0f ? acc * inv + bo[c] : 0.0f;
}

// ---------------------------------------------------------------- launch
extern "C" void kernel_launch(void* const* d_in, const int* in_sizes, int n_in,
                              void* d_out, int out_size, void* d_ws, size_t ws_size,
                              hipStream_t stream) {
    const float* x     = (const float*)d_in[0];
    const int*   ei    = (const int*)d_in[1];
    const int*   batch = (const int*)d_in[2];
    const float* W_in  = (const float*)d_in[3];
    const float* b_in  = (const float*)d_in[4];
    const float* W1_0  = (const float*)d_in[5];
    const float* b1_0  = (const float*)d_in[6];
    const float* W2_0  = (const float*)d_in[7];
    const float* b2_0  = (const float*)d_in[8];
    const float* W1_1  = (const float*)d_in[9];
    const float* b1_1  = (const float*)d_in[10];
    const float* W2_1  = (const float*)d_in[11];
    const float* b2_1  = (const float*)d_in[12];
    const float* W_out = (const float*)d_in[13];
    const float* b_out = (const float*)d_in[14];
    float* out = (float*)d_out;

    unsigned int* wsw = (unsigned int*)d_ws;
    int*          gcur   = (int*)(wsw + OFF_GCUR);
    float*        sums   = (float*)(wsw + OFF_SUMS);
    float*        cnts   = (float*)(wsw + OFF_CNT);
    int*          rowptr = (int*)(wsw + OFF_ROWPTR);
    __half*       hH     = (__half*)(wsw + OFF_HH);
    float*        v      = (float*)(wsw + OFF_V);
    unsigned int* epairs = (unsigned int*)(wsw + OFF_V);   // dead before k_aggr writes v
    int*          srcl   = (int*)(wsw + OFF_SRCL);

    const int pi_blocks  = (N_NODES + 63) / 64;       // 782
    const int mlp_blocks = (N_NODES + 127) / 128;     // 391
    const int ag_blocks  = N_NODES / 16;              // 3125 (exact)
    const int pool_blocks = (N_NODES + 4 * POOL_CHUNK - 1) / (4 * POOL_CHUNK);  // 98

    k_zero<<<64, 256, 0, stream>>>(wsw, ZERO_WORDS);
    k_bucket<<<NBKT, 256, 0, stream>>>(ei, gcur, epairs);
    k_csr<<<NBKT, 256, 0, stream>>>(gcur, epairs, rowptr, srcl);

    k_proj_in<<<pi_blocks, 256, 0, stream>>>(x, W_in, b_in, hH);
    // conv 0
    k_aggr<<<ag_blocks, 256, 0, stream>>>(hH, rowptr, srcl, v);
    k_mlp<<<mlp_blocks, 256, 0, stream>>>(v, W1_0, b1_0, W2_0, b2_0, hH);
    // conv 1
    k_aggr<<<ag_blocks, 256, 0, stream>>>(hH, rowptr, srcl, v);
    k_mlp<<<mlp_blocks, 256, 0, stream>>>(v, W1_1, b1_1, W2_1, b2_1, hH);
    // pool then tiny proj_out
    k_pool<<<pool_blocks, 256, 0, stream>>>(hH, batch, sums, cnts);
    k_pfinal<<<(N_GRAPHS * OUT_DIM) / 256, 256, 0, stream>>>(sums, cnts, W_out, b_out, out);
}

// Round 6
// 284.124 us; speedup vs baseline: 6.3119x; 1.0557x over previous
//
#include <hip/hip_runtime.h>
#include <hip/hip_fp16.h>

// Problem constants (fixed by the reference)
#define N_NODES   50000
#define N_EDGES   800000
#define IN_DIM    128
#define HID       64
#define OUT_DIM   128
#define N_GRAPHS  128

#define NBKT      196        // ceil(50000/256) coarse dst-buckets
#define BSTRIDE   5120       // slots/bucket (mean 4096, 16-sigma margin)
#define CAP       40         // LDS staging depth per bucket (pass A)

// Workspace layout in 4-byte words.
#define OFF_GCUR   0                    // int[196] (zeroed)
#define ZERO_WORDS 196
#define OFF_SUMS   196                  // float[128*64] (fully written by k_pool2)
#define OFF_CNT    8388                 // float[128]   (fully written by k_pool2)
#define OFF_GSTART 8516                 // int[130]     (fully written by k_gbound)
#define OFF_ROWPTR 8648                 // int[50001]
#define OFF_HH     58652                // __half[50000*64] = 1,600,000 words (16B aligned)
#define OFF_V      1658652              // float[3,200,000]; epairs uint32[196*5120] aliases here
#define OFF_SRCL   4858652              // int[800000]
// end = 5,658,652 words = 22.6 MB

// ---------------------------------------------------------------- zero fill
__global__ void k_zero(unsigned int* __restrict__ p, int n) {
    int i = blockIdx.x * blockDim.x + threadIdx.x;
    int stride = gridDim.x * blockDim.x;
    for (; i < n; i += stride) p[i] = 0u;
}

// ---------------------------------------------------------------- pass A: coarse bucket scatter
__global__ __launch_bounds__(256) void k_bucket(const int* __restrict__ ei,
                                                int* __restrict__ gcur,
                                                unsigned int* __restrict__ epairs) {
    __shared__ int lcnt[NBKT];
    __shared__ unsigned int stage[NBKT * CAP];   // 31.4 KB
    const int t = threadIdx.x;
    for (int i = t; i < NBKT; i += 256) lcnt[i] = 0;
    __syncthreads();
    for (int e0 = blockIdx.x * 256; e0 < N_EDGES; e0 += gridDim.x * 256) {
        const int e = e0 + t;
        if (e < N_EDGES) {
            const unsigned int src = (unsigned int)ei[e];
            const unsigned int dst = (unsigned int)ei[N_EDGES + e];
            const int b = dst >> 8;
            const unsigned int pk = src | (dst << 16);   // both < 2^16
            const int pos = atomicAdd(&lcnt[b], 1);
            if (pos < CAP) stage[b * CAP + pos] = pk;
            else {  // rare overflow: direct scattered write
                const int gp = atomicAdd(&gcur[b], 1);
                epairs[b * BSTRIDE + gp] = pk;
            }
        }
        __syncthreads();
        if (t < NBKT) {
            int n = lcnt[t]; if (n > CAP) n = CAP;
            if (n >= 16) {
                const int f = n & ~15;               // 64B-aligned chunks
                const int base = atomicAdd(&gcur[t], f);
                for (int i = 0; i < f; ++i)
                    epairs[t * BSTRIDE + base + i] = stage[t * CAP + i];
                for (int i = 0; i < n - f; ++i)
                    stage[t * CAP + i] = stage[t * CAP + f + i];
                lcnt[t] = n - f;
            } else {
                lcnt[t] = n;
            }
        }
        __syncthreads();
    }
    if (t < NBKT) {
        const int n = lcnt[t];
        if (n > 0) {
            const int base = atomicAdd(&gcur[t], n);
            for (int i = 0; i < n; ++i)
                epairs[t * BSTRIDE + base + i] = stage[t * CAP + i];
        }
    }
}

// ---------------------------------------------------------------- pass B: per-bucket CSR in LDS
__global__ __launch_bounds__(256) void k_csr(const int* __restrict__ gcur,
                                             const unsigned int* __restrict__ epairs,
                                             int* __restrict__ rowptr,
                                             int* __restrict__ srclist) {
    __shared__ int lhist[256];
    __shared__ int lcur[256];
    __shared__ int lsrc[BSTRIDE];     // 20.5 KB
    __shared__ int pws[4], wtot[4];
    const int b = blockIdx.x;
    const int t = threadIdx.x;
    const int lane = t & 63, wv = t >> 6;

    int po = 0;
    for (int j = t; j < b; j += 256) po += gcur[j];
#pragma unroll
    for (int m = 32; m; m >>= 1) po += __shfl_xor(po, m, 64);
    if (lane == 0) pws[wv] = po;
    lhist[t] = 0;
    __syncthreads();
    const int base = pws[0] + pws[1] + pws[2] + pws[3];
    const int cnt = gcur[b];

    for (int i = t; i < cnt; i += 256)
        atomicAdd(&lhist[(epairs[b * BSTRIDE + i] >> 16) & 255], 1);
    __syncthreads();

    const int d = lhist[t];
    int incl = d;
#pragma unroll
    for (int off = 1; off < 64; off <<= 1) {
        const int u = __shfl_up(incl, off, 64);
        if (lane >= off) incl += u;
    }
    if (lane == 63) wtot[wv] = incl;
    __syncthreads();
    int woff = 0;
#pragma unroll
    for (int i = 0; i < 4; ++i) woff += (i < wv) ? wtot[i] : 0;
    const int excl = woff + incl - d;
    lcur[t] = excl;
    const int node = b * 256 + t;
    if (node < N_NODES) rowptr[node] = base + excl;
    if (b == NBKT - 1 && t == 0) rowptr[N_NODES] = base + cnt;  // == N_EDGES
    __syncthreads();

    for (int i = t; i < cnt; i += 256) {
        const unsigned int u = epairs[b * BSTRIDE + i];
        const int pos = atomicAdd(&lcur[(u >> 16) & 255], 1);
        lsrc[pos] = (int)(u & 0xFFFFu);
    }
    __syncthreads();
    for (int i = t; i < cnt; i += 256) srclist[base + i] = lsrc[i];
}

// ---------------------------------------------------------------- graph boundaries (batch is sorted)
// gstart[g] = first node of graph g; covers empty graphs; gstart[128] = N_NODES.
__global__ __launch_bounds__(256) void k_gbound(const int* __restrict__ batch,
                                                int* __restrict__ gstart) {
    const int n = blockIdx.x * blockDim.x + threadIdx.x;
    if (n >= N_NODES) return;
    const int b = batch[n];
    if (n == 0) {
        for (int g = 0; g <= b; ++g) gstart[g] = 0;
    } else {
        const int p = batch[n - 1];
        for (int g = p + 1; g <= b; ++g) gstart[g] = n;
    }
    if (n == N_NODES - 1) {
        for (int g = b + 1; g <= N_GRAPHS; ++g) gstart[g] = N_NODES;
    }
}

// ---------------------------------------------------------------- proj_in (fp16 output)
#define S_X 129
union H8 { float4 f4; __half2 h[4]; };
__global__ __launch_bounds__(256) void k_proj_in(
        const float* __restrict__ x, const float* __restrict__ W,
        const float* __restrict__ b, __half* __restrict__ hH) {
    __shared__ float A[64 * S_X];           // 33 KB
    __shared__ float Wl[IN_DIM * HID];      // 32 KB
    const int t = threadIdx.x;
    for (int i = t; i < IN_DIM * HID; i += 256) Wl[i] = W[i];
    const int nb = blockIdx.x * 64;
    for (int i = t; i < 64 * (IN_DIM / 4); i += 256) {
        const int n = i >> 5;
        const int k4 = (i & 31) * 4;
        float4 val = make_float4(0.f, 0.f, 0.f, 0.f);
        if (nb + n < N_NODES)
            val = *(const float4*)(x + (size_t)(nb + n) * IN_DIM + k4);
        float* dst = &A[n * S_X + k4];
        dst[0] = val.x; dst[1] = val.y; dst[2] = val.z; dst[3] = val.w;
    }
    __syncthreads();

    const int ln = t & 31;
    const int c0 = (t >> 5) * 8;
    float acc[2][8];
#pragma unroll
    for (int j = 0; j < 2; ++j)
#pragma unroll
        for (int c = 0; c < 8; ++c) acc[j][c] = b[c0 + c];
    for (int k = 0; k < IN_DIM; ++k) {
        const float a0 = A[ln * S_X + k];
        const float a1 = A[(ln + 32) * S_X + k];
        const float4 wA = *(const float4*)&Wl[k * HID + c0];
        const float4 wB = *(const float4*)&Wl[k * HID + c0 + 4];
        const float w[8] = {wA.x, wA.y, wA.z, wA.w, wB.x, wB.y, wB.z, wB.w};
#pragma unroll
        for (int c = 0; c < 8; ++c) {
            acc[0][c] = fmaf(a0, w[c], acc[0][c]);
            acc[1][c] = fmaf(a1, w[c], acc[1][c]);
        }
    }
#pragma unroll
    for (int j = 0; j < 2; ++j) {
        const int n = nb + ln + 32 * j;
        if (n < N_NODES) {
            H8 o;
#pragma unroll
            for (int c = 0; c < 4; ++c)
                o.h[c] = __floats2half2_rn(acc[j][2 * c], acc[j][2 * c + 1]);
            *(float4*)(hH + (size_t)n * HID + c0) = o.f4;
        }
    }
}

// ---------------------------------------------------------------- aggregation (fp16 gather, fp32 acc)
__device__ inline void acc_h4(float4& a, const float2 r) {
    const __half2 h0 = *(const __half2*)&r.x;
    const __half2 h1 = *(const __half2*)&r.y;
    const float2 f0 = __half22float2(h0);
    const float2 f1 = __half22float2(h1);
    a.x += f0.x; a.y += f0.y; a.z += f1.x; a.w += f1.y;
}

__global__ __launch_bounds__(256) void k_aggr(
        const __half* __restrict__ hH,
        const int* __restrict__ rowptr, const int* __restrict__ srclist,
        float* __restrict__ v) {
    const int t = threadIdx.x;
    const int wv = t >> 6;
    const int lane = t & 63;
    const int g = lane >> 4;          // node group (0..3)
    const int q = lane & 15;          // 4-elem chunk (0..15)
    const int node = blockIdx.x * 16 + wv * 4 + g;   // N_NODES = 3125*16 exact

    const int beg = rowptr[node];
    const int end = rowptr[node + 1];

    float4 acc = make_float4(0.f, 0.f, 0.f, 0.f);
    acc_h4(acc, *(const float2*)(hH + (size_t)node * HID + q * 4));   // self

    int e = beg;
    for (; e + 4 <= end; e += 4) {
        const int s0 = srclist[e];
        const int s1 = srclist[e + 1];
        const int s2 = srclist[e + 2];
        const int s3 = srclist[e + 3];
        const float2 r0 = *(const float2*)(hH + (size_t)s0 * HID + q * 4);
        const float2 r1 = *(const float2*)(hH + (size_t)s1 * HID + q * 4);
        const float2 r2 = *(const float2*)(hH + (size_t)s2 * HID + q * 4);
        const float2 r3 = *(const float2*)(hH + (size_t)s3 * HID + q * 4);
        acc_h4(acc, r0); acc_h4(acc, r1); acc_h4(acc, r2); acc_h4(acc, r3);
    }
    for (; e < end; ++e)
        acc_h4(acc, *(const float2*)(hH + (size_t)srclist[e] * HID + q * 4));

    *(float4*)(v + (size_t)node * HID + q * 4) = acc;
}

// ---------------------------------------------------------------- GIN MLP (fp32 in, fp16 out)
#define S_A 65
__global__ __launch_bounds__(256) void k_mlp(
        const float* __restrict__ v,
        const float* __restrict__ W1, const float* __restrict__ b1,
        const float* __restrict__ W2, const float* __restrict__ b2,
        __half* __restrict__ hH) {
    __shared__ float A[128 * S_A];          // 33.3 KB
    __shared__ float Wl[2 * HID * HID];     // 32 KB
    const int t = threadIdx.x;
    for (int i = t; i < HID * HID; i += 256) {
        Wl[i] = W1[i];
        Wl[HID * HID + i] = W2[i];
    }
    const int nb = blockIdx.x * 128;
    for (int i = t; i < 128 * (HID / 4); i += 256) {
        const int n = i >> 4;
        const int k4 = (i & 15) * 4;
        float4 val = make_float4(0.f, 0.f, 0.f, 0.f);
        if (nb + n < N_NODES)
            val = *(const float4*)(v + (size_t)(nb + n) * HID + k4);
        float* dst = &A[n * S_A + k4];
        dst[0] = val.x; dst[1] = val.y; dst[2] = val.z; dst[3] = val.w;
    }
    __syncthreads();

    const int ln = t & 31;
    const int c0 = (t >> 5) * 8;
    float bb1[8], bb2[8];
#pragma unroll
    for (int c = 0; c < 8; ++c) { bb1[c] = b1[c0 + c]; bb2[c] = b2[c0 + c]; }

    float acc[4][8];
#pragma unroll
    for (int j = 0; j < 4; ++j)
#pragma unroll
        for (int c = 0; c < 8; ++c) acc[j][c] = bb1[c];
    for (int k = 0; k < HID; ++k) {
        float a[4];
#pragma unroll
        for (int j = 0; j < 4; ++j) a[j] = A[(ln + 32 * j) * S_A + k];
        const float4 wA = *(const float4*)&Wl[k * HID + c0];
        const float4 wB = *(const float4*)&Wl[k * HID + c0 + 4];
        const float w[8] = {wA.x, wA.y, wA.z, wA.w, wB.x, wB.y, wB.z, wB.w};
#pragma unroll
        for (int j = 0; j < 4; ++j)
#pragma unroll
            for (int c = 0; c < 8; ++c)
                acc[j][c] = fmaf(a[j], w[c], acc[j][c]);
    }
    __syncthreads();
#pragma unroll
    for (int j = 0; j < 4; ++j) {
        float* dst = &A[(ln + 32 * j) * S_A + c0];
#pragma unroll
        for (int c = 0; c < 8; ++c) dst[c] = fmaxf(acc[j][c], 0.0f);
    }
    __syncthreads();

#pragma unroll
    for (int j = 0; j < 4; ++j)
#pragma unroll
        for (int c = 0; c < 8; ++c) acc[j][c] = bb2[c];
    for (int k = 0; k < HID; ++k) {
        float a[4];
#pragma unroll
        for (int j = 0; j < 4; ++j) a[j] = A[(ln + 32 * j) * S_A + k];
        const float4 wA = *(const float4*)&Wl[HID * HID + k * HID + c0];
        const float4 wB = *(const float4*)&Wl[HID * HID + k * HID + c0 + 4];
        const float w[8] = {wA.x, wA.y, wA.z, wA.w, wB.x, wB.y, wB.z, wB.w};
#pragma unroll
        for (int j = 0; j < 4; ++j)
#pragma unroll
            for (int c = 0; c < 8; ++c)
                acc[j][c] = fmaf(a[j], w[c], acc[j][c]);
    }
#pragma unroll
    for (int j = 0; j < 4; ++j) {
        const int n = nb + ln + 32 * j;
        if (n < N_NODES) {
            H8 o;
#pragma unroll
            for (int c = 0; c < 4; ++c)
                o.h[c] = __floats2half2_rn(fmaxf(acc[j][2 * c], 0.f),
                                           fmaxf(acc[j][2 * c + 1], 0.f));
            *(float4*)(hH + (size_t)n * HID + c0) = o.f4;
        }
    }
}

// ---------------------------------------------------------------- pool: block per graph, branch-free
__global__ __launch_bounds__(256) void k_pool2(
        const __half* __restrict__ hH, const int* __restrict__ gstart,
        float* __restrict__ sums, float* __restrict__ cnts) {
    __shared__ float red[4][HID];
    const int g = blockIdx.x;
    const int t = threadIdx.x;
    const int c = t & 63;
    const int wv = t >> 6;
    const int beg = gstart[g], end = gstart[g + 1];
    float acc = 0.0f;
    for (int n = beg + wv; n < end; n += 4)
        acc += __half2float(hH[(size_t)n * HID + c]);
    red[wv][c] = acc;
    __syncthreads();
    if (t < HID) {
        sums[g * HID + t] = red[0][t] + red[1][t] + red[2][t] + red[3][t];
        if (t == 0) cnts[g] = (float)(end - beg);
    }
}

// ---------------------------------------------------------------- pooled proj_out
__global__ __launch_bounds__(256) void k_pfinal(
        const float* __restrict__ sums, const float* __restrict__ cnts,
        const float* __restrict__ Wo, const float* __restrict__ bo,
        float* __restrict__ out) {
    __shared__ float Wl[HID * OUT_DIM];   // 32 KB
    const int t = threadIdx.x;
    for (int i = t; i < HID * OUT_DIM; i += 256) Wl[i] = Wo[i];
    __syncthreads();
    const int idx = blockIdx.x * 256 + t;
    const int g = idx >> 7;
    const int c = idx & 127;
    const float cnt = cnts[g];
    const float inv = cnt > 0.0f ? 1.0f / cnt : 0.0f;
    float acc = 0.0f;
    for (int k = 0; k < HID; ++k)
        acc = fmaf(sums[g * HID + k], Wl[k * OUT_DIM + c], acc);
    out[idx] = cnt > 0.0f ? acc * inv + bo[c] : 0.0f;
}

// ---------------------------------------------------------------- launch
extern "C" void kernel_launch(void* const* d_in, const int* in_sizes, int n_in,
                              void* d_out, int out_size, void* d_ws, size_t ws_size,
                              hipStream_t stream) {
    const float* x     = (const float*)d_in[0];
    const int*   ei    = (const int*)d_in[1];
    const int*   batch = (const int*)d_in[2];
    const float* W_in  = (const float*)d_in[3];
    const float* b_in  = (const float*)d_in[4];
    const float* W1_0  = (const float*)d_in[5];
    const float* b1_0  = (const float*)d_in[6];
    const float* W2_0  = (const float*)d_in[7];
    const float* b2_0  = (const float*)d_in[8];
    const float* W1_1  = (const float*)d_in[9];
    const float* b1_1  = (const float*)d_in[10];
    const float* W2_1  = (const float*)d_in[11];
    const float* b2_1  = (const float*)d_in[12];
    const float* W_out = (const float*)d_in[13];
    const float* b_out = (const float*)d_in[14];
    float* out = (float*)d_out;

    unsigned int* wsw = (unsigned int*)d_ws;
    int*          gcur   = (int*)(wsw + OFF_GCUR);
    float*        sums   = (float*)(wsw + OFF_SUMS);
    float*        cnts   = (float*)(wsw + OFF_CNT);
    int*          gstart = (int*)(wsw + OFF_GSTART);
    int*          rowptr = (int*)(wsw + OFF_ROWPTR);
    __half*       hH     = (__half*)(wsw + OFF_HH);
    float*        v      = (float*)(wsw + OFF_V);
    unsigned int* epairs = (unsigned int*)(wsw + OFF_V);   // dead before k_aggr writes v
    int*          srcl   = (int*)(wsw + OFF_SRCL);

    const int pi_blocks  = (N_NODES + 63) / 64;       // 782
    const int mlp_blocks = (N_NODES + 127) / 128;     // 391
    const int ag_blocks  = N_NODES / 16;              // 3125 (exact)

    k_zero<<<1, 256, 0, stream>>>(wsw, ZERO_WORDS);
    k_gbound<<<NBKT, 256, 0, stream>>>(batch, gstart);
    k_bucket<<<NBKT, 256, 0, stream>>>(ei, gcur, epairs);
    k_csr<<<NBKT, 256, 0, stream>>>(gcur, epairs, rowptr, srcl);

    k_proj_in<<<pi_blocks, 256, 0, stream>>>(x, W_in, b_in, hH);
    // conv 0
    k_aggr<<<ag_blocks, 256, 0, stream>>>(hH, rowptr, srcl, v);
    k_mlp<<<mlp_blocks, 256, 0, stream>>>(v, W1_0, b1_0, W2_0, b2_0, hH);
    // conv 1
    k_aggr<<<ag_blocks, 256, 0, stream>>>(hH, rowptr, srcl, v);
    k_mlp<<<mlp_blocks, 256, 0, stream>>>(v, W1_1, b1_1, W2_1, b2_1, hH);
    // pool then tiny proj_out
    k_pool2<<<N_GRAPHS, 256, 0, stream>>>(hH, gstart, sums, cnts);
    k_pfinal<<<(N_GRAPHS * OUT_DIM) / 256, 256, 0, stream>>>(sums, cnts, W_out, b_out, out);
}